// Round 1
// baseline (164.502 us; speedup 1.0000x reference)
//
#include <hip/hip_runtime.h>
#include <math.h>

// SDE Euler-Maruyama path generator.
// x_{k+1} = x_k + (A x_k + b) dt + (C x_k + d) * (sqrt(dt)*eps_k)   elementwise on the noise term
// B=4096 paths, T=2500 steps, D=3. One thread per path; noise prefetched in
// double-buffered register chunks (named buffers only -> no scratch spill).

constexpr int B_N  = 4096;
constexpr int T_N  = 2500;
constexpr int CH   = 10;          // steps per prefetch chunk
constexpr int NCH  = T_N / CH;    // 250 (even)

__global__ __launch_bounds__(64)
void sde_paths_kernel(const float* __restrict__ x0,
                      const float* __restrict__ A,
                      const float* __restrict__ bv,
                      const float* __restrict__ C,
                      const float* __restrict__ dv,
                      const float* __restrict__ noise,
                      float* __restrict__ out)
{
    const int b = blockIdx.x * 64 + threadIdx.x;
    if (b >= B_N) return;

    const float dt  = 0.002f;
    const float sdt = sqrtf(dt);

    // Fold dt into drift, sqrt(dt) into diffusion (uniform scalar loads).
    float Adt[3][3], Cs[3][3], bdt[3], ds[3];
#pragma unroll
    for (int i = 0; i < 3; ++i) {
        bdt[i] = bv[i] * dt;
        ds[i]  = dv[i] * sdt;
#pragma unroll
        for (int j = 0; j < 3; ++j) {
            Adt[i][j] = A[i * 3 + j] * dt;
            Cs[i][j]  = C[i * 3 + j] * sdt;
        }
    }

    float x0r = x0[b * 3 + 0];
    float x1r = x0[b * 3 + 1];
    float x2r = x0[b * 3 + 2];

    float* __restrict__ op = out + (size_t)b * (T_N + 1) * 3;
    op[0] = x0r; op[1] = x1r; op[2] = x2r;
    op += 3;

    const float* __restrict__ nb = noise + (size_t)b * 3;   // noise[t][b][c] @ t*B*3 + b*3 + c
    const size_t nstride = (size_t)B_N * 3;

    float bufA[CH][3], bufB[CH][3];

    auto loadChunk = [&](float (&buf)[CH][3], int cbase) {
#pragma unroll
        for (int k = 0; k < CH; ++k) {
            const float* p = nb + ((size_t)cbase * CH + k) * nstride;
            buf[k][0] = p[0];
            buf[k][1] = p[1];
            buf[k][2] = p[2];
        }
    };

    auto compChunk = [&](const float (&buf)[CH][3]) {
#pragma unroll
        for (int k = 0; k < CH; ++k) {
            const float e0 = buf[k][0], e1 = buf[k][1], e2 = buf[k][2];

            const float a0 = fmaf(Adt[0][2], x2r, fmaf(Adt[0][1], x1r, fmaf(Adt[0][0], x0r, bdt[0])));
            const float a1 = fmaf(Adt[1][2], x2r, fmaf(Adt[1][1], x1r, fmaf(Adt[1][0], x0r, bdt[1])));
            const float a2 = fmaf(Adt[2][2], x2r, fmaf(Adt[2][1], x1r, fmaf(Adt[2][0], x0r, bdt[2])));

            const float c0 = fmaf(Cs[0][2], x2r, fmaf(Cs[0][1], x1r, fmaf(Cs[0][0], x0r, ds[0])));
            const float c1 = fmaf(Cs[1][2], x2r, fmaf(Cs[1][1], x1r, fmaf(Cs[1][0], x0r, ds[1])));
            const float c2 = fmaf(Cs[2][2], x2r, fmaf(Cs[2][1], x1r, fmaf(Cs[2][0], x0r, ds[2])));

            const float n0 = fmaf(c0, e0, x0r + a0);
            const float n1 = fmaf(c1, e1, x1r + a1);
            const float n2 = fmaf(c2, e2, x2r + a2);

            op[0] = n0; op[1] = n1; op[2] = n2;
            op += 3;

            x0r = n0; x1r = n1; x2r = n2;
        }
    };

    // Prologue: chunk 0 in flight.
    loadChunk(bufA, 0);

    // Software-pipelined: issue next chunk's loads before computing current.
    for (int c = 0; c < NCH; c += 2) {
        if (c + 1 < NCH) loadChunk(bufB, c + 1);
        compChunk(bufA);
        if (c + 2 < NCH) loadChunk(bufA, c + 2);
        if (c + 1 < NCH) compChunk(bufB);
    }
}

extern "C" void kernel_launch(void* const* d_in, const int* in_sizes, int n_in,
                              void* d_out, int out_size, void* d_ws, size_t ws_size,
                              hipStream_t stream) {
    const float* x0    = (const float*)d_in[0];
    const float* A     = (const float*)d_in[1];
    const float* bv    = (const float*)d_in[2];
    const float* C     = (const float*)d_in[3];
    const float* dv    = (const float*)d_in[4];
    const float* noise = (const float*)d_in[5];
    float* out = (float*)d_out;

    sde_paths_kernel<<<B_N / 64, 64, 0, stream>>>(x0, A, bv, C, dv, noise, out);
}

// Round 2
// 122.689 us; speedup vs baseline: 1.3408x; 1.3408x over previous
//
#include <hip/hip_runtime.h>
#include <math.h>

// SDE Euler-Maruyama path generator — affine-scan decomposition.
//   step:  x' = S_k x + t_k,  S_k = I + dt*A + diag(dW_k)*C,  t_k = dt*b + dW_k*d
// Phase 1: per (path, chunk) compose L step-affines -> (M, v)        [B*NC threads]
// Phase 2: per path, serial scan over NC chunk affines -> boundary x [B threads]
// Phase 3: per (path, chunk) replay L Euler steps from boundary      [B*NC threads]

constexpr int B_N  = 4096;
constexpr int T_N  = 2500;
constexpr int L    = 50;           // steps per chunk
constexpr int NC   = T_N / L;      // 50 chunks
constexpr int SUB  = 10;           // noise prefetch sub-chunk
constexpr int NSUB = L / SUB;      // 5

// d_ws layout (floats):
//   trans: [NC][B][12]   (M row-major 9, then v 3)       9.83 MB
//   bnd:   [NC][B][4]    (chunk-start state, padded)     3.28 MB
constexpr size_t TRANS_FLOATS = (size_t)NC * B_N * 12;
constexpr size_t BND_OFF      = TRANS_FLOATS;

__global__ __launch_bounds__(64)
void sde_chunk_transforms(const float* __restrict__ A,
                          const float* __restrict__ bv,
                          const float* __restrict__ C,
                          const float* __restrict__ dv,
                          const float* __restrict__ noise,
                          float* __restrict__ trans)
{
    const int b = blockIdx.x * 64 + threadIdx.x;
    const int c = blockIdx.y;

    const float dt  = 0.002f;
    const float sdt = sqrtf(dt);

    float IA[3][3], Cs[3][3], bdt[3], ds[3];
#pragma unroll
    for (int i = 0; i < 3; ++i) {
        bdt[i] = bv[i] * dt;
        ds[i]  = dv[i] * sdt;
#pragma unroll
        for (int j = 0; j < 3; ++j) {
            IA[i][j] = A[i * 3 + j] * dt + (i == j ? 1.0f : 0.0f);
            Cs[i][j] = C[i * 3 + j] * sdt;
        }
    }

    // accumulated affine: x_out = M x + v
    float M[3][3] = {{1,0,0},{0,1,0},{0,0,1}};
    float v[3] = {0, 0, 0};

    const float* __restrict__ nb = noise + (size_t)c * L * (B_N * 3) + (size_t)b * 3;
    const size_t nstride = (size_t)B_N * 3;

    float bufA[SUB][3], bufB[SUB][3];

    auto loadChunk = [&](float (&buf)[SUB][3], int s) {
#pragma unroll
        for (int k = 0; k < SUB; ++k) {
            const float* p = nb + ((size_t)s * SUB + k) * nstride;
            buf[k][0] = p[0];
            buf[k][1] = p[1];
            buf[k][2] = p[2];
        }
    };

    auto compChunk = [&](const float (&buf)[SUB][3]) {
#pragma unroll
        for (int k = 0; k < SUB; ++k) {
            const float e[3] = { buf[k][0], buf[k][1], buf[k][2] };
            float S[3][3], t[3];
#pragma unroll
            for (int i = 0; i < 3; ++i) {
                t[i] = fmaf(e[i], ds[i], bdt[i]);
#pragma unroll
                for (int j = 0; j < 3; ++j)
                    S[i][j] = fmaf(e[i], Cs[i][j], IA[i][j]);
            }
            float nM[3][3], nv[3];
#pragma unroll
            for (int i = 0; i < 3; ++i) {
#pragma unroll
                for (int j = 0; j < 3; ++j)
                    nM[i][j] = fmaf(S[i][2], M[2][j], fmaf(S[i][1], M[1][j], S[i][0] * M[0][j]));
                nv[i] = fmaf(S[i][2], v[2], fmaf(S[i][1], v[1], S[i][0] * v[0])) + t[i];
            }
#pragma unroll
            for (int i = 0; i < 3; ++i) {
                v[i] = nv[i];
#pragma unroll
                for (int j = 0; j < 3; ++j) M[i][j] = nM[i][j];
            }
        }
    };

    loadChunk(bufA, 0);
    for (int s = 0; s < NSUB; s += 2) {
        if (s + 1 < NSUB) loadChunk(bufB, s + 1);
        compChunk(bufA);
        if (s + 2 < NSUB) loadChunk(bufA, s + 2);
        if (s + 1 < NSUB) compChunk(bufB);
    }

    float* tp = trans + ((size_t)c * B_N + b) * 12;
    float4 w0 = { M[0][0], M[0][1], M[0][2], M[1][0] };
    float4 w1 = { M[1][1], M[1][2], M[2][0], M[2][1] };
    float4 w2 = { M[2][2], v[0],    v[1],    v[2]    };
    ((float4*)tp)[0] = w0;
    ((float4*)tp)[1] = w1;
    ((float4*)tp)[2] = w2;
}

__global__ __launch_bounds__(64)
void sde_scan(const float* __restrict__ x0,
              const float* __restrict__ trans,
              float* __restrict__ bnd,
              float* __restrict__ out)
{
    const int b = blockIdx.x * 64 + threadIdx.x;

    float x[3] = { x0[b * 3 + 0], x0[b * 3 + 1], x0[b * 3 + 2] };

    float* op = out + (size_t)b * (T_N + 1) * 3;
    op[0] = x[0]; op[1] = x[1]; op[2] = x[2];

    // double-buffered prefetch of chunk affines
    const float4* tp0 = (const float4*)(trans + (size_t)b * 12);
    const size_t cstride4 = (size_t)B_N * 3;  // in float4 units: B*12 floats / 4

    float4 a0 = tp0[0], a1 = tp0[1], a2 = tp0[2];

    for (int c = 0; c < NC; ++c) {
        float4 b0, b1, b2;
        if (c + 1 < NC) {
            const float4* tn = tp0 + (size_t)(c + 1) * cstride4;
            b0 = tn[0]; b1 = tn[1]; b2 = tn[2];
        }

        float* bp = bnd + ((size_t)c * B_N + b) * 4;
        ((float4*)bp)[0] = make_float4(x[0], x[1], x[2], 0.0f);

        const float n0 = fmaf(a0.x, x[0], fmaf(a0.y, x[1], fmaf(a0.z, x[2], a2.y)));
        const float n1 = fmaf(a0.w, x[0], fmaf(a1.x, x[1], fmaf(a1.y, x[2], a2.z)));
        const float n2 = fmaf(a1.z, x[0], fmaf(a1.w, x[1], fmaf(a2.x, x[2], a2.w)));
        x[0] = n0; x[1] = n1; x[2] = n2;

        a0 = b0; a1 = b1; a2 = b2;
    }
}

__global__ __launch_bounds__(64)
void sde_replay(const float* __restrict__ A,
                const float* __restrict__ bv,
                const float* __restrict__ C,
                const float* __restrict__ dv,
                const float* __restrict__ noise,
                const float* __restrict__ bnd,
                float* __restrict__ out)
{
    const int b = blockIdx.x * 64 + threadIdx.x;
    const int c = blockIdx.y;

    const float dt  = 0.002f;
    const float sdt = sqrtf(dt);

    float Adt[3][3], Cs[3][3], bdt[3], ds[3];
#pragma unroll
    for (int i = 0; i < 3; ++i) {
        bdt[i] = bv[i] * dt;
        ds[i]  = dv[i] * sdt;
#pragma unroll
        for (int j = 0; j < 3; ++j) {
            Adt[i][j] = A[i * 3 + j] * dt;
            Cs[i][j]  = C[i * 3 + j] * sdt;
        }
    }

    const float4 xb = *(const float4*)(bnd + ((size_t)c * B_N + b) * 4);
    float x0r = xb.x, x1r = xb.y, x2r = xb.z;

    float* __restrict__ op = out + (size_t)b * (T_N + 1) * 3 + (size_t)(c * L + 1) * 3;

    const float* __restrict__ nb = noise + (size_t)c * L * (B_N * 3) + (size_t)b * 3;
    const size_t nstride = (size_t)B_N * 3;

    float bufA[SUB][3], bufB[SUB][3];

    auto loadChunk = [&](float (&buf)[SUB][3], int s) {
#pragma unroll
        for (int k = 0; k < SUB; ++k) {
            const float* p = nb + ((size_t)s * SUB + k) * nstride;
            buf[k][0] = p[0];
            buf[k][1] = p[1];
            buf[k][2] = p[2];
        }
    };

    auto compChunk = [&](const float (&buf)[SUB][3]) {
#pragma unroll
        for (int k = 0; k < SUB; ++k) {
            const float e0 = buf[k][0], e1 = buf[k][1], e2 = buf[k][2];

            const float a0 = fmaf(Adt[0][2], x2r, fmaf(Adt[0][1], x1r, fmaf(Adt[0][0], x0r, bdt[0])));
            const float a1 = fmaf(Adt[1][2], x2r, fmaf(Adt[1][1], x1r, fmaf(Adt[1][0], x0r, bdt[1])));
            const float a2 = fmaf(Adt[2][2], x2r, fmaf(Adt[2][1], x1r, fmaf(Adt[2][0], x0r, bdt[2])));

            const float c0 = fmaf(Cs[0][2], x2r, fmaf(Cs[0][1], x1r, fmaf(Cs[0][0], x0r, ds[0])));
            const float c1 = fmaf(Cs[1][2], x2r, fmaf(Cs[1][1], x1r, fmaf(Cs[1][0], x0r, ds[1])));
            const float c2 = fmaf(Cs[2][2], x2r, fmaf(Cs[2][1], x1r, fmaf(Cs[2][0], x0r, ds[2])));

            const float n0 = fmaf(c0, e0, x0r + a0);
            const float n1 = fmaf(c1, e1, x1r + a1);
            const float n2 = fmaf(c2, e2, x2r + a2);

            op[0] = n0; op[1] = n1; op[2] = n2;
            op += 3;

            x0r = n0; x1r = n1; x2r = n2;
        }
    };

    loadChunk(bufA, 0);
    for (int s = 0; s < NSUB; s += 2) {
        if (s + 1 < NSUB) loadChunk(bufB, s + 1);
        compChunk(bufA);
        if (s + 2 < NSUB) loadChunk(bufA, s + 2);
        if (s + 1 < NSUB) compChunk(bufB);
    }
}

extern "C" void kernel_launch(void* const* d_in, const int* in_sizes, int n_in,
                              void* d_out, int out_size, void* d_ws, size_t ws_size,
                              hipStream_t stream) {
    const float* x0    = (const float*)d_in[0];
    const float* A     = (const float*)d_in[1];
    const float* bv    = (const float*)d_in[2];
    const float* C     = (const float*)d_in[3];
    const float* dv    = (const float*)d_in[4];
    const float* noise = (const float*)d_in[5];
    float* out = (float*)d_out;

    float* trans = (float*)d_ws;
    float* bnd   = trans + BND_OFF;

    dim3 gridPC(B_N / 64, NC);

    sde_chunk_transforms<<<gridPC, 64, 0, stream>>>(A, bv, C, dv, noise, trans);
    sde_scan<<<B_N / 64, 64, 0, stream>>>(x0, trans, bnd, out);
    sde_replay<<<gridPC, 64, 0, stream>>>(A, bv, C, dv, noise, bnd, out);
}

// Round 3
// 95.716 us; speedup vs baseline: 1.7186x; 1.2818x over previous
//
#include <hip/hip_runtime.h>
#include <math.h>

// SDE Euler-Maruyama path generator — affine-scan decomposition.
//   step:  x' = S_k x + t_k,  S_k = I + dt*A + diag(dW_k)*C,  t_k = dt*b + dW_k*d
// Phase 1: per (path, chunk) compose L step-affines -> (M, v)        [B*NC threads]
// Phase 2: per path, serial scan over NC chunk affines -> boundary x [B threads]
// Phase 3: per (path, chunk) replay L Euler steps from boundary.
//          Output is transposed through a wave-private LDS tile so global
//          stores are line-coalesced (no RFO / write amplification).

constexpr int B_N  = 4096;
constexpr int T_N  = 2500;
constexpr int L    = 50;           // steps per chunk
constexpr int NC   = T_N / L;      // 50 chunks
constexpr int FL   = 10;           // steps per flush/prefetch sub-chunk
constexpr int NFL  = L / FL;       // 5
constexpr int ROWF = (T_N + 1) * 3; // floats per output path row

// d_ws layout (floats):
//   trans: [NC][B][12]   (M row-major 9, then v 3)       9.83 MB
//   bnd:   [NC][B][4]    (chunk-start state, padded)     3.28 MB
constexpr size_t TRANS_FLOATS = (size_t)NC * B_N * 12;
constexpr size_t BND_OFF      = TRANS_FLOATS;

__global__ __launch_bounds__(64)
void sde_chunk_transforms(const float* __restrict__ A,
                          const float* __restrict__ bv,
                          const float* __restrict__ C,
                          const float* __restrict__ dv,
                          const float* __restrict__ noise,
                          float* __restrict__ trans)
{
    const int b = blockIdx.x * 64 + threadIdx.x;
    const int c = blockIdx.y;

    const float dt  = 0.002f;
    const float sdt = sqrtf(dt);

    float IA[3][3], Cs[3][3], bdt[3], ds[3];
#pragma unroll
    for (int i = 0; i < 3; ++i) {
        bdt[i] = bv[i] * dt;
        ds[i]  = dv[i] * sdt;
#pragma unroll
        for (int j = 0; j < 3; ++j) {
            IA[i][j] = A[i * 3 + j] * dt + (i == j ? 1.0f : 0.0f);
            Cs[i][j] = C[i * 3 + j] * sdt;
        }
    }

    float M[3][3] = {{1,0,0},{0,1,0},{0,0,1}};
    float v[3] = {0, 0, 0};

    const float* __restrict__ nb = noise + (size_t)c * L * (B_N * 3) + (size_t)b * 3;
    const size_t nstride = (size_t)B_N * 3;

    float bufA[FL][3], bufB[FL][3];

    auto loadChunk = [&](float (&buf)[FL][3], int s) {
#pragma unroll
        for (int k = 0; k < FL; ++k) {
            const float* p = nb + ((size_t)s * FL + k) * nstride;
            buf[k][0] = p[0];
            buf[k][1] = p[1];
            buf[k][2] = p[2];
        }
    };

    auto compChunk = [&](const float (&buf)[FL][3]) {
#pragma unroll
        for (int k = 0; k < FL; ++k) {
            const float e[3] = { buf[k][0], buf[k][1], buf[k][2] };
            float S[3][3], t[3];
#pragma unroll
            for (int i = 0; i < 3; ++i) {
                t[i] = fmaf(e[i], ds[i], bdt[i]);
#pragma unroll
                for (int j = 0; j < 3; ++j)
                    S[i][j] = fmaf(e[i], Cs[i][j], IA[i][j]);
            }
            float nM[3][3], nv[3];
#pragma unroll
            for (int i = 0; i < 3; ++i) {
#pragma unroll
                for (int j = 0; j < 3; ++j)
                    nM[i][j] = fmaf(S[i][2], M[2][j], fmaf(S[i][1], M[1][j], S[i][0] * M[0][j]));
                nv[i] = fmaf(S[i][2], v[2], fmaf(S[i][1], v[1], S[i][0] * v[0])) + t[i];
            }
#pragma unroll
            for (int i = 0; i < 3; ++i) {
                v[i] = nv[i];
#pragma unroll
                for (int j = 0; j < 3; ++j) M[i][j] = nM[i][j];
            }
        }
    };

    loadChunk(bufA, 0);
    for (int s = 0; s < NFL; s += 2) {
        if (s + 1 < NFL) loadChunk(bufB, s + 1);
        compChunk(bufA);
        if (s + 2 < NFL) loadChunk(bufA, s + 2);
        if (s + 1 < NFL) compChunk(bufB);
    }

    float* tp = trans + ((size_t)c * B_N + b) * 12;
    float4 w0 = { M[0][0], M[0][1], M[0][2], M[1][0] };
    float4 w1 = { M[1][1], M[1][2], M[2][0], M[2][1] };
    float4 w2 = { M[2][2], v[0],    v[1],    v[2]    };
    ((float4*)tp)[0] = w0;
    ((float4*)tp)[1] = w1;
    ((float4*)tp)[2] = w2;
}

__global__ __launch_bounds__(64)
void sde_scan(const float* __restrict__ x0,
              const float* __restrict__ trans,
              float* __restrict__ bnd,
              float* __restrict__ out)
{
    const int b = blockIdx.x * 64 + threadIdx.x;

    float x[3] = { x0[b * 3 + 0], x0[b * 3 + 1], x0[b * 3 + 2] };

    float* op = out + (size_t)b * ROWF;
    op[0] = x[0]; op[1] = x[1]; op[2] = x[2];

    const float4* tp0 = (const float4*)(trans + (size_t)b * 12);
    const size_t cstride4 = (size_t)B_N * 3;

    float4 a0 = tp0[0], a1 = tp0[1], a2 = tp0[2];

    for (int c = 0; c < NC; ++c) {
        float4 b0, b1, b2;
        if (c + 1 < NC) {
            const float4* tn = tp0 + (size_t)(c + 1) * cstride4;
            b0 = tn[0]; b1 = tn[1]; b2 = tn[2];
        }

        float* bp = bnd + ((size_t)c * B_N + b) * 4;
        ((float4*)bp)[0] = make_float4(x[0], x[1], x[2], 0.0f);

        const float n0 = fmaf(a0.x, x[0], fmaf(a0.y, x[1], fmaf(a0.z, x[2], a2.y)));
        const float n1 = fmaf(a0.w, x[0], fmaf(a1.x, x[1], fmaf(a1.y, x[2], a2.z)));
        const float n2 = fmaf(a1.z, x[0], fmaf(a1.w, x[1], fmaf(a2.x, x[2], a2.w)));
        x[0] = n0; x[1] = n1; x[2] = n2;

        a0 = b0; a1 = b1; a2 = b2;
    }
}

__global__ __launch_bounds__(256)
void sde_replay(const float* __restrict__ A,
                const float* __restrict__ bv,
                const float* __restrict__ C,
                const float* __restrict__ dv,
                const float* __restrict__ noise,
                const float* __restrict__ bnd,
                float* __restrict__ out)
{
    __shared__ float lds[4][64][31];

    const int widx = threadIdx.x >> 6;
    const int lane = threadIdx.x & 63;
    const int wg   = blockIdx.x * 4 + widx;   // 0..3199
    const int pg   = wg & 63;                 // path group (64 groups of 64)
    const int c    = wg >> 6;                 // chunk 0..49
    const int b    = (pg << 6) | lane;

    const float dt  = 0.002f;
    const float sdt = sqrtf(dt);

    float Adt[3][3], Cs[3][3], bdt[3], dsv[3];
#pragma unroll
    for (int i = 0; i < 3; ++i) {
        bdt[i] = bv[i] * dt;
        dsv[i] = dv[i] * sdt;
#pragma unroll
        for (int j = 0; j < 3; ++j) {
            Adt[i][j] = A[i * 3 + j] * dt;
            Cs[i][j]  = C[i * 3 + j] * sdt;
        }
    }

    const float4 xb = *(const float4*)(bnd + ((size_t)c * B_N + b) * 4);
    float x0r = xb.x, x1r = xb.y, x2r = xb.z;

    const float* __restrict__ nb = noise + (size_t)c * L * (B_N * 3) + (size_t)b * 3;
    const size_t nstride = (size_t)B_N * 3;

    float (*tile)[31] = lds[widx];

    // store-role constants: instr i writes paths {2i, 2i+1}
    const int  half = lane >> 5;              // 0 or 1
    const int  r    = lane & 31;              // 0..31
    const bool act  = r < 30;
    // float-unit store base: path pg*64+half, time offset (c*L+1), elem r
    float* __restrict__ sb = out + (size_t)((pg << 6) + half) * ROWF
                                 + (size_t)(c * L + 1) * 3 + r;

    float bufA[FL][3], bufB[FL][3];

    auto loadChunk = [&](float (&buf)[FL][3], int s) {
#pragma unroll
        for (int k = 0; k < FL; ++k) {
            const float* p = nb + ((size_t)s * FL + k) * nstride;
            buf[k][0] = p[0];
            buf[k][1] = p[1];
            buf[k][2] = p[2];
        }
    };

    auto doFlush = [&](const float (&buf)[FL][3], int fl) {
        // ---- compute FL steps into registers ----
        float st[FL][3];
#pragma unroll
        for (int k = 0; k < FL; ++k) {
            const float e0 = buf[k][0], e1 = buf[k][1], e2 = buf[k][2];

            const float a0 = fmaf(Adt[0][2], x2r, fmaf(Adt[0][1], x1r, fmaf(Adt[0][0], x0r, bdt[0])));
            const float a1 = fmaf(Adt[1][2], x2r, fmaf(Adt[1][1], x1r, fmaf(Adt[1][0], x0r, bdt[1])));
            const float a2 = fmaf(Adt[2][2], x2r, fmaf(Adt[2][1], x1r, fmaf(Adt[2][0], x0r, bdt[2])));

            const float c0 = fmaf(Cs[0][2], x2r, fmaf(Cs[0][1], x1r, fmaf(Cs[0][0], x0r, dsv[0])));
            const float c1 = fmaf(Cs[1][2], x2r, fmaf(Cs[1][1], x1r, fmaf(Cs[1][0], x0r, dsv[1])));
            const float c2 = fmaf(Cs[2][2], x2r, fmaf(Cs[2][1], x1r, fmaf(Cs[2][0], x0r, dsv[2])));

            const float n0 = fmaf(c0, e0, x0r + a0);
            const float n1 = fmaf(c1, e1, x1r + a1);
            const float n2 = fmaf(c2, e2, x2r + a2);

            st[k][0] = n0; st[k][1] = n1; st[k][2] = n2;
            x0r = n0; x1r = n1; x2r = n2;
        }

        // ---- WAR guard: previous round's LDS reads must be done ----
        asm volatile("s_waitcnt lgkmcnt(0)" ::: "memory");

        // ---- write own 30 floats to LDS row (stride 31 -> 2-way, free) ----
#pragma unroll
        for (int k = 0; k < FL; ++k) {
            tile[lane][k * 3 + 0] = st[k][0];
            tile[lane][k * 3 + 1] = st[k][1];
            tile[lane][k * 3 + 2] = st[k][2];
        }

        // ---- RAW guard before cross-lane reads ----
        asm volatile("s_waitcnt lgkmcnt(0)" ::: "memory");
        __builtin_amdgcn_sched_barrier(0);

        // ---- transposed, line-coalesced global stores ----
        if (act) {
#pragma unroll
            for (int i = 0; i < 32; ++i) {
                const float val = tile[2 * i + half][r];
                sb[(size_t)(2 * i) * ROWF + fl * (FL * 3)] = val;
            }
        }
    };

    loadChunk(bufA, 0);
    loadChunk(bufB, 1);
    doFlush(bufA, 0);
    loadChunk(bufA, 2);
    doFlush(bufB, 1);
    loadChunk(bufB, 3);
    doFlush(bufA, 2);
    loadChunk(bufA, 4);
    doFlush(bufB, 3);
    doFlush(bufA, 4);
}

extern "C" void kernel_launch(void* const* d_in, const int* in_sizes, int n_in,
                              void* d_out, int out_size, void* d_ws, size_t ws_size,
                              hipStream_t stream) {
    const float* x0    = (const float*)d_in[0];
    const float* A     = (const float*)d_in[1];
    const float* bv    = (const float*)d_in[2];
    const float* C     = (const float*)d_in[3];
    const float* dv    = (const float*)d_in[4];
    const float* noise = (const float*)d_in[5];
    float* out = (float*)d_out;

    float* trans = (float*)d_ws;
    float* bnd   = trans + BND_OFF;

    dim3 gridPC(B_N / 64, NC);

    sde_chunk_transforms<<<gridPC, 64, 0, stream>>>(A, bv, C, dv, noise, trans);
    sde_scan<<<B_N / 64, 64, 0, stream>>>(x0, trans, bnd, out);
    sde_replay<<<(B_N / 64) * NC / 4, 256, 0, stream>>>(A, bv, C, dv, noise, bnd, out);
}